// Round 6
// baseline (445.506 us; speedup 1.0000x reference)
//
#include <hip/hip_runtime.h>
#include <math.h>

#define N_NODES 50000
#define N_EDGES 800000
#define ET (N_EDGES + N_NODES)   // with self-loops
#define FDIM 128
#define HEADS 4
#define HID 32
#define NCLS 8
#define NEG 0.2f
#define EPS_BN 1e-5f

#define BSH 5                                   // 32 nodes per bucket
#define NBUCK ((N_NODES + 31) >> BSH)           // 1563

typedef __attribute__((ext_vector_type(8))) short short8;
typedef __attribute__((ext_vector_type(4))) float f32x4;

__device__ __forceinline__ float lrelu(float e) { return e > 0.f ? e : NEG * e; }
__device__ __forceinline__ float bflo(unsigned u) { return __uint_as_float(u << 16); }
__device__ __forceinline__ float bfhi(unsigned u) { return __uint_as_float(u & 0xffff0000u); }
__device__ __forceinline__ unsigned f2bf(float f) {           // RNE round to bf16 bits
    unsigned b = __float_as_uint(f);
    return (b + 0x7fffu + ((b >> 16) & 1u)) >> 16;
}

// ---------------- graph prep ----------------

__global__ void count_deg(const int* __restrict__ ei, int* __restrict__ cnt) {
    int e = blockIdx.x * blockDim.x + threadIdx.x;
    if (e >= ET) return;
    int d = (e < N_EDGES) ? ei[N_EDGES + e] : (e - N_EDGES);
    atomicAdd(&cnt[d], 1);
}

__global__ void scan_partial(const int* __restrict__ cnt, int* __restrict__ offs,
                             int* __restrict__ bsums) {
    __shared__ int s[256];
    int tid = threadIdx.x;
    int i = blockIdx.x * 256 + tid;
    int v = (i < N_NODES) ? cnt[i] : 0;
    s[tid] = v;
    __syncthreads();
    for (int off = 1; off < 256; off <<= 1) {
        int x = (tid >= off) ? s[tid - off] : 0;
        __syncthreads();
        s[tid] += x;
        __syncthreads();
    }
    if (i < N_NODES) offs[i] = s[tid] - v;
    if (tid == 255) bsums[blockIdx.x] = s[255];
}

__global__ void scan_root(const int* __restrict__ bsums, int* __restrict__ boffs, int nb) {
    __shared__ int s[256];
    int tid = threadIdx.x;
    int v = (tid < nb) ? bsums[tid] : 0;
    s[tid] = v;
    __syncthreads();
    for (int off = 1; off < 256; off <<= 1) {
        int x = (tid >= off) ? s[tid - off] : 0;
        __syncthreads();
        s[tid] += x;
        __syncthreads();
    }
    boffs[tid] = s[tid] - v;
}

// offs finalize + bucket-cursor init (bcur[b] = offs[b<<BSH])
__global__ void scan_add(int* __restrict__ offs, const int* __restrict__ boffs,
                         const int* __restrict__ bsums, int* __restrict__ bcur, int nb) {
    int i = blockIdx.x * 256 + threadIdx.x;
    if (i < N_NODES) {
        int v = offs[i] + boffs[blockIdx.x];
        offs[i] = v;
        if ((i & ((1 << BSH) - 1)) == 0) bcur[i >> BSH] = v;
    }
    if (i == 0) offs[N_NODES] = boffs[nb - 1] + bsums[nb - 1];
}

// pass A: append (src,dst) pairs into coarse bucket regions (same space as final CSR)
__global__ void scatter_pairs(const int* __restrict__ ei, int* __restrict__ bcur,
                              int2* __restrict__ pairs) {
    int e = blockIdx.x * blockDim.x + threadIdx.x;
    if (e >= ET) return;
    int s, d;
    if (e < N_EDGES) { s = ei[e]; d = ei[N_EDGES + e]; }
    else             { s = d = e - N_EDGES; }
    int pos = atomicAdd(&bcur[d >> BSH], 1);
    pairs[pos] = make_int2(s, d);
}

// pass B: within each bucket region, group by node via LDS cursors
__global__ __launch_bounds__(256) void group_bucket(const int2* __restrict__ pairs,
                                                    const int* __restrict__ offs,
                                                    int* __restrict__ ssrc) {
    __shared__ int lcur[1 << BSH];
    int b = blockIdx.x, tid = threadIdx.x;
    int n0 = b << BSH;
    int base = offs[n0];
    int nend = n0 + (1 << BSH); if (nend > N_NODES) nend = N_NODES;
    int regionEnd = offs[nend];
    if (tid < (1 << BSH))
        lcur[tid] = (n0 + tid < N_NODES) ? (offs[n0 + tid] - base) : 0;
    __syncthreads();
    for (int i = base + tid; i < regionEnd; i += 256) {
        int2 p = pairs[i];
        int pos = atomicAdd(&lcur[p.y & ((1 << BSH) - 1)], 1);
        ssrc[base + pos] = p.x;
    }
}

// ---------------- fused input prep: x->bf16 cast + W0/W1 fragment packing ----------------

#define CAST_B 3125   // 50000*128/8/256
#define PACK_B 64     // 16384/256

__global__ void prep_inputs(const float* __restrict__ x, unsigned short* __restrict__ xb,
                            const float* __restrict__ W0, unsigned short* __restrict__ W0p,
                            const float* __restrict__ W1, unsigned short* __restrict__ W1p) {
    int b = blockIdx.x, tid = threadIdx.x;
    if (b < CAST_B) {
        int i = b * 256 + tid;
        const float4* p = (const float4*)x + (size_t)i * 2;
        float4 a = p[0], c = p[1];
        uint4 o;
        o.x = f2bf(a.x) | (f2bf(a.y) << 16);
        o.y = f2bf(a.z) | (f2bf(a.w) << 16);
        o.z = f2bf(c.x) | (f2bf(c.y) << 16);
        o.w = f2bf(c.z) | (f2bf(c.w) << 16);
        ((uint4*)xb)[i] = o;
    } else {
        int pb = b - CAST_B;
        const float* W = (pb < PACK_B) ? W0 : W1;
        unsigned short* Wp = (pb < PACK_B) ? W0p : W1p;
        int o = (pb & (PACK_B - 1)) * 256 + tid;
        int j = o & 7, lane = (o >> 3) & 63, kc = (o >> 9) & 3, t = o >> 11;
        int k = kc * 32 + ((lane >> 4) << 3) + j;
        int n = t * 16 + (lane & 15);
        Wp[o] = (unsigned short)f2bf(W[k * 128 + n]);
    }
}

// ------- fused MFMA GEMM (M x 128 @ 128 x 128) + bf16 h-store + attn coeffs -------

__global__ __launch_bounds__(256) void gemm_attn(
        const unsigned short* __restrict__ Ab, const unsigned short* __restrict__ Wp,
        const float* __restrict__ att_s, const float* __restrict__ att_d,
        unsigned short* __restrict__ Hb, float* __restrict__ asn, float* __restrict__ adn,
        int M) {
    __shared__ float tiles[64 * 132];
    int tid = threadIdx.x;
    int wv = tid >> 6, lane = tid & 63;
    int base = blockIdx.x * 64;
    int mrow = base + wv * 16 + (lane & 15);
    if (mrow >= M) mrow = M - 1;
    int koff = (lane >> 4) * 8;

    f32x4 acc[8];
    #pragma unroll
    for (int t = 0; t < 8; t++) acc[t] = (f32x4){0.f, 0.f, 0.f, 0.f};

    #pragma unroll
    for (int kc = 0; kc < 4; kc++) {
        short8 a = *(const short8*)(Ab + (size_t)mrow * 128 + kc * 32 + koff);
        #pragma unroll
        for (int t = 0; t < 8; t++) {
            short8 b = *(const short8*)(Wp + (((t * 4 + kc) * 64 + lane) << 3));
            acc[t] = __builtin_amdgcn_mfma_f32_16x16x32_bf16(a, b, acc[t], 0, 0, 0);
        }
    }

    int rbase = wv * 16 + (lane >> 4) * 4;
    int col = lane & 15;
    #pragma unroll
    for (int t = 0; t < 8; t++)
        #pragma unroll
        for (int r = 0; r < 4; r++)
            tiles[(rbase + r) * 132 + t * 16 + col] = acc[t][r];
    __syncthreads();

    #pragma unroll
    for (int it = 0; it < 4; it++) {
        int u = tid + it * 256;
        int rl = u >> 4, cg = u & 15;
        int row = base + rl;
        if (row < M) {
            const float* p = tiles + rl * 132 + cg * 8;
            float4 v0 = *(const float4*)(p);
            float4 v1 = *(const float4*)(p + 4);
            uint4 o;
            o.x = f2bf(v0.x) | (f2bf(v0.y) << 16);
            o.y = f2bf(v0.z) | (f2bf(v0.w) << 16);
            o.z = f2bf(v1.x) | (f2bf(v1.y) << 16);
            o.w = f2bf(v1.z) | (f2bf(v1.w) << 16);
            *(uint4*)(Hb + (size_t)row * 128 + cg * 8) = o;
        }
    }

    {
        int rl = tid >> 2, hd = tid & 3;
        int row = base + rl;
        if (row < M) {
            const float* hrow = tiles + rl * 132 + hd * 32;
            const float* as = att_s + hd * 32;
            const float* ad = att_d + hd * 32;
            float ps = 0.f, pd = 0.f;
            #pragma unroll
            for (int i = 0; i < 8; i++) {
                float4 hv = *(const float4*)(hrow + i * 4);
                float4 sv = *(const float4*)(as + i * 4);
                float4 dv = *(const float4*)(ad + i * 4);
                ps += hv.x * sv.x + hv.y * sv.y + hv.z * sv.z + hv.w * sv.w;
                pd += hv.x * dv.x + hv.y * dv.y + hv.z * dv.z + hv.w * dv.w;
            }
            asn[row * 4 + hd] = ps;
            adn[row * 4 + hd] = pd;
        }
    }
}

// ------- aggregation + bias + BN + ELU (layers 0,1): one wave/node, channel-parallel -------
// lane owns channels {2*lane, 2*lane+1}; head = lane>>4. Phase C: per edge one coalesced
// 256 B bf16 row; 8-edge unroll (8 gathers in flight); no accumulator reduction needed.

__global__ __launch_bounds__(256) void aggregate(
        const unsigned short* __restrict__ hb, const float* __restrict__ asn,
        const float* __restrict__ adn, const int* __restrict__ offs,
        const int* __restrict__ ssrc, const float* __restrict__ bias,
        const float* __restrict__ gamma, const float* __restrict__ beta,
        const float* __restrict__ rmean, const float* __restrict__ rvar,
        unsigned short* __restrict__ outb) {
    __shared__ int2 sPair[4][4][72];   // [wave][head][slot]; stride 72 -> heads offset 16 banks
    int wv = threadIdx.x >> 6;
    int node = blockIdx.x * 4 + wv;
    if (node >= N_NODES) return;
    int lane = threadIdx.x & 63;
    int hd = lane >> 4;
    int beg = offs[node], deg = offs[node + 1] - beg;
    float4 ad4 = *(const float4*)(adn + node * 4);

    // zero pad slots 64..71 (unroll-8 overrun; w=0 -> harmless)
    if (lane < 32) sPair[wv][lane >> 3][64 + (lane & 7)] = make_int2(0, 0);

    int s0 = 0;
    float4 e4 = make_float4(-1e30f, -1e30f, -1e30f, -1e30f);
    if (lane < deg) {
        s0 = ssrc[beg + lane];
        float4 a = *(const float4*)(asn + s0 * 4);
        e4.x = lrelu(a.x + ad4.x); e4.y = lrelu(a.y + ad4.y);
        e4.z = lrelu(a.z + ad4.z); e4.w = lrelu(a.w + ad4.w);
    }
    float4 m4 = e4;
    for (int base = 64; base < deg; base += 64) {   // rare
        int j = base + lane;
        if (j < deg) {
            int s = ssrc[beg + j];
            float4 a = *(const float4*)(asn + s * 4);
            m4.x = fmaxf(m4.x, lrelu(a.x + ad4.x));
            m4.y = fmaxf(m4.y, lrelu(a.y + ad4.y));
            m4.z = fmaxf(m4.z, lrelu(a.z + ad4.z));
            m4.w = fmaxf(m4.w, lrelu(a.w + ad4.w));
        }
    }
    #pragma unroll
    for (int off = 32; off; off >>= 1) {
        m4.x = fmaxf(m4.x, __shfl_xor(m4.x, off));
        m4.y = fmaxf(m4.y, __shfl_xor(m4.y, off));
        m4.z = fmaxf(m4.z, __shfl_xor(m4.z, off));
        m4.w = fmaxf(m4.w, __shfl_xor(m4.w, off));
    }

    float4 den4 = make_float4(0.f, 0.f, 0.f, 0.f);
    float acc0 = 0.f, acc1 = 0.f;
    const unsigned short* hlane = hb + 2 * lane;
    const int2* pp = &sPair[wv][hd][0];

    auto phaseC = [&](int cnt) {
        int bound = (cnt + 7) & ~7;
        for (int i = 0; i < bound; i += 8) {
            int2 p0 = pp[i],     p1 = pp[i + 1], p2 = pp[i + 2], p3 = pp[i + 3];
            int2 p4 = pp[i + 4], p5 = pp[i + 5], p6 = pp[i + 6], p7 = pp[i + 7];
            unsigned u0 = *(const unsigned*)(hlane + (((unsigned)p0.x) << 7));
            unsigned u1 = *(const unsigned*)(hlane + (((unsigned)p1.x) << 7));
            unsigned u2 = *(const unsigned*)(hlane + (((unsigned)p2.x) << 7));
            unsigned u3 = *(const unsigned*)(hlane + (((unsigned)p3.x) << 7));
            unsigned u4 = *(const unsigned*)(hlane + (((unsigned)p4.x) << 7));
            unsigned u5 = *(const unsigned*)(hlane + (((unsigned)p5.x) << 7));
            unsigned u6 = *(const unsigned*)(hlane + (((unsigned)p6.x) << 7));
            unsigned u7 = *(const unsigned*)(hlane + (((unsigned)p7.x) << 7));
            acc0 += __int_as_float(p0.y) * bflo(u0); acc1 += __int_as_float(p0.y) * bfhi(u0);
            acc0 += __int_as_float(p1.y) * bflo(u1); acc1 += __int_as_float(p1.y) * bfhi(u1);
            acc0 += __int_as_float(p2.y) * bflo(u2); acc1 += __int_as_float(p2.y) * bfhi(u2);
            acc0 += __int_as_float(p3.y) * bflo(u3); acc1 += __int_as_float(p3.y) * bfhi(u3);
            acc0 += __int_as_float(p4.y) * bflo(u4); acc1 += __int_as_float(p4.y) * bfhi(u4);
            acc0 += __int_as_float(p5.y) * bflo(u5); acc1 += __int_as_float(p5.y) * bfhi(u5);
            acc0 += __int_as_float(p6.y) * bflo(u6); acc1 += __int_as_float(p6.y) * bfhi(u6);
            acc0 += __int_as_float(p7.y) * bflo(u7); acc1 += __int_as_float(p7.y) * bfhi(u7);
        }
    };

    {
        float4 w4 = make_float4(0.f, 0.f, 0.f, 0.f);
        if (lane < deg) {
            w4.x = __expf(e4.x - m4.x); w4.y = __expf(e4.y - m4.y);
            w4.z = __expf(e4.z - m4.z); w4.w = __expf(e4.w - m4.w);
            den4.x += w4.x; den4.y += w4.y; den4.z += w4.z; den4.w += w4.w;
        }
        sPair[wv][0][lane] = make_int2(s0, __float_as_int(w4.x));
        sPair[wv][1][lane] = make_int2(s0, __float_as_int(w4.y));
        sPair[wv][2][lane] = make_int2(s0, __float_as_int(w4.z));
        sPair[wv][3][lane] = make_int2(s0, __float_as_int(w4.w));
        phaseC(deg < 64 ? deg : 64);
    }
    for (int base = 64; base < deg; base += 64) {
        int j = base + lane;
        int s = 0;
        float4 w4 = make_float4(0.f, 0.f, 0.f, 0.f);
        if (j < deg) {
            s = ssrc[beg + j];
            float4 a = *(const float4*)(asn + s * 4);
            w4.x = __expf(lrelu(a.x + ad4.x) - m4.x);
            w4.y = __expf(lrelu(a.y + ad4.y) - m4.y);
            w4.z = __expf(lrelu(a.z + ad4.z) - m4.z);
            w4.w = __expf(lrelu(a.w + ad4.w) - m4.w);
            den4.x += w4.x; den4.y += w4.y; den4.z += w4.z; den4.w += w4.w;
        }
        sPair[wv][0][lane] = make_int2(s, __float_as_int(w4.x));
        sPair[wv][1][lane] = make_int2(s, __float_as_int(w4.y));
        sPair[wv][2][lane] = make_int2(s, __float_as_int(w4.z));
        sPair[wv][3][lane] = make_int2(s, __float_as_int(w4.w));
        int cnt = deg - base; if (cnt > 64) cnt = 64;
        phaseC(cnt);
    }

    #pragma unroll
    for (int off = 32; off; off >>= 1) {
        den4.x += __shfl_xor(den4.x, off);
        den4.y += __shfl_xor(den4.y, off);
        den4.z += __shfl_xor(den4.z, off);
        den4.w += __shfl_xor(den4.w, off);
    }
    float den = (hd & 2) ? ((hd & 1) ? den4.w : den4.z)
                         : ((hd & 1) ? den4.y : den4.x);
    float inv = 1.f / (den + 1e-16f);

    int c0 = lane * 2;
    float2 bi = *(const float2*)(bias + c0);
    float2 gm = *(const float2*)(gamma + c0);
    float2 bt = *(const float2*)(beta + c0);
    float2 rm = *(const float2*)(rmean + c0);
    float2 rv = *(const float2*)(rvar + c0);
    float o0 = acc0 * inv + bi.x;
    float o1 = acc1 * inv + bi.y;
    o0 = (o0 - rm.x) * rsqrtf(rv.x + EPS_BN) * gm.x + bt.x;
    o1 = (o1 - rm.y) * rsqrtf(rv.y + EPS_BN) * gm.y + bt.y;
    o0 = (o0 > 0.f) ? o0 : expm1f(o0);
    o1 = (o1 > 0.f) ? o1 : expm1f(o1);
    *(unsigned*)(outb + (size_t)node * 128 + c0) = f2bf(o0) | (f2bf(o1) << 16);
}

// ---------------- layer 2: fused GEMM(128->8) + attn coeffs (bf16 input) ----------------

__global__ __launch_bounds__(256) void gemm2_fused(
        const unsigned short* __restrict__ xb, const float* __restrict__ W2,
        const float* __restrict__ as2, const float* __restrict__ ad2,
        float* __restrict__ h2, float* __restrict__ asn, float* __restrict__ adn) {
    __shared__ float sW[128 * 8];
    __shared__ float sas[8], sad[8];
    int tid = threadIdx.x;
    for (int i = tid; i < 1024; i += 256) sW[i] = W2[i];
    if (tid < 8) { sas[tid] = as2[tid]; sad[tid] = ad2[tid]; }
    __syncthreads();
    int node = blockIdx.x * 256 + tid;
    if (node >= N_NODES) return;
    const uint4* xr = (const uint4*)(xb + (size_t)node * 128);
    float acc[8];
    #pragma unroll
    for (int c = 0; c < 8; c++) acc[c] = 0.f;
    for (int k8 = 0; k8 < 16; k8++) {
        uint4 u = xr[k8];
        float f[8] = { bflo(u.x), bfhi(u.x), bflo(u.y), bfhi(u.y),
                       bflo(u.z), bfhi(u.z), bflo(u.w), bfhi(u.w) };
        int kb = k8 * 8;
        #pragma unroll
        for (int q = 0; q < 8; q++)
            #pragma unroll
            for (int c = 0; c < 8; c++)
                acc[c] += f[q] * sW[(kb + q) * 8 + c];
    }
    float ps = 0.f, pd = 0.f;
    #pragma unroll
    for (int c = 0; c < 8; c++) {
        h2[(size_t)node * 8 + c] = acc[c];
        ps += acc[c] * sas[c];
        pd += acc[c] * sad[c];
    }
    asn[node] = ps;
    adn[node] = pd;
}

// ------- layer 2 aggregation + bias + log_softmax: one wave/node -------

__global__ __launch_bounds__(256) void aggregate2(
        const float* __restrict__ h2, const float* __restrict__ asn,
        const float* __restrict__ adn, const int* __restrict__ offs,
        const int* __restrict__ ssrc, const float* __restrict__ b2,
        float* __restrict__ out) {
    __shared__ int2 sPair[4][64];
    int wv = threadIdx.x >> 6;
    int node = blockIdx.x * 4 + wv;
    if (node >= N_NODES) return;
    int lane = threadIdx.x & 63;
    int g = lane >> 3, c = lane & 7;
    int beg = offs[node], end = offs[node + 1];
    int deg = end - beg;
    float adv = adn[node];

    int s0 = 0;
    float e0v = -1e30f;
    if (lane < deg) {
        s0 = ssrc[beg + lane];
        e0v = lrelu(asn[s0] + adv);
    }
    float m = e0v;
    for (int base = 64; base < deg; base += 64) {
        int j = base + lane;
        if (j < deg) m = fmaxf(m, lrelu(asn[ssrc[beg + j]] + adv));
    }
    #pragma unroll
    for (int off = 32; off; off >>= 1) m = fmaxf(m, __shfl_xor(m, off));

    float den = 0.f, acc = 0.f;
    auto phaseC = [&](int cnt) {
        int nIt = (cnt + 15) >> 4;
        const int2* pp = &sPair[wv][0];
        for (int i = 0; i < nIt; i++) {
            int e = i * 16 + g;
            int2 p0 = pp[e];
            int2 p1 = pp[e + 8];
            acc += __int_as_float(p0.y) * h2[(((unsigned)p0.x) << 3) + c];
            acc += __int_as_float(p1.y) * h2[(((unsigned)p1.x) << 3) + c];
        }
    };

    {
        float w = 0.f;
        if (lane < deg) { w = __expf(e0v - m); den += w; }
        sPair[wv][lane] = make_int2(s0, __float_as_int(w));
        int cnt = deg < 64 ? deg : 64;
        phaseC(cnt);
    }
    for (int base = 64; base < deg; base += 64) {
        int j = base + lane;
        int s = 0; float w = 0.f;
        if (j < deg) {
            s = ssrc[beg + j];
            w = __expf(lrelu(asn[s] + adv) - m);
            den += w;
        }
        sPair[wv][lane] = make_int2(s, __float_as_int(w));
        int cnt = deg - base; if (cnt > 64) cnt = 64;
        phaseC(cnt);
    }

    acc += __shfl_xor(acc, 8); acc += __shfl_xor(acc, 16); acc += __shfl_xor(acc, 32);
    #pragma unroll
    for (int off = 32; off; off >>= 1) den += __shfl_xor(den, off);

    float o = acc / (den + 1e-16f) + b2[c];
    float mx = o;
    mx = fmaxf(mx, __shfl_xor(mx, 1));
    mx = fmaxf(mx, __shfl_xor(mx, 2));
    mx = fmaxf(mx, __shfl_xor(mx, 4));
    float ex = __expf(o - mx);
    float sm = ex;
    sm += __shfl_xor(sm, 1); sm += __shfl_xor(sm, 2); sm += __shfl_xor(sm, 4);
    if (g == 0) out[(size_t)node * 8 + c] = o - mx - logf(sm);
}

// ---------------- launch ----------------

extern "C" void kernel_launch(void* const* d_in, const int* in_sizes, int n_in,
                              void* d_out, int out_size, void* d_ws, size_t ws_size,
                              hipStream_t stream) {
    const float* x   = (const float*)d_in[0];
    const int*   ei  = (const int*)d_in[1];
    const float* W0  = (const float*)d_in[2];
    const float* as0 = (const float*)d_in[3];
    const float* ad0 = (const float*)d_in[4];
    const float* b0  = (const float*)d_in[5];
    const float* g0  = (const float*)d_in[6];
    const float* bb0 = (const float*)d_in[7];
    const float* rm0 = (const float*)d_in[8];
    const float* rv0 = (const float*)d_in[9];
    const float* W1  = (const float*)d_in[10];
    const float* as1 = (const float*)d_in[11];
    const float* ad1 = (const float*)d_in[12];
    const float* b1  = (const float*)d_in[13];
    const float* g1  = (const float*)d_in[14];
    const float* bb1 = (const float*)d_in[15];
    const float* rm1 = (const float*)d_in[16];
    const float* rv1 = (const float*)d_in[17];
    const float* W2  = (const float*)d_in[18];
    const float* as2 = (const float*)d_in[19];
    const float* ad2 = (const float*)d_in[20];
    const float* b2  = (const float*)d_in[21];
    float* out = (float*)d_out;

    char* w = (char*)d_ws;
    size_t off = 0;
    auto carve = [&](size_t bytes) {
        void* p = w + off;
        off += (bytes + 255) & ~(size_t)255;
        return p;
    };
    unsigned short* xb   = (unsigned short*)carve((size_t)N_NODES * 128 * 2);
    unsigned short* Hb   = (unsigned short*)carve((size_t)N_NODES * 128 * 2);
    unsigned short* Xb   = (unsigned short*)carve((size_t)N_NODES * 128 * 2);
    unsigned short* W0p  = (unsigned short*)carve(16384 * 2);
    unsigned short* W1p  = (unsigned short*)carve(16384 * 2);
    int*   cnt    = (int*)carve((size_t)N_NODES * 4);
    int*   offs   = (int*)carve((size_t)(N_NODES + 1) * 4);
    int*   bcur   = (int*)carve((size_t)NBUCK * 4);
    int*   bsums  = (int*)carve(1024);
    int*   boffs  = (int*)carve(1024);
    int*   ssrc   = (int*)carve((size_t)ET * 4);
    int2*  pairs  = (int2*)carve((size_t)ET * 8);
    float* asn    = (float*)carve((size_t)N_NODES * 4 * 4);
    float* adn    = (float*)carve((size_t)N_NODES * 4 * 4);
    float* h2     = (float*)carve((size_t)N_NODES * 8 * 4);
    float* as2n   = (float*)carve((size_t)N_NODES * 4);
    float* ad2n   = (float*)carve((size_t)N_NODES * 4);
    (void)ws_size; (void)in_sizes; (void)n_in; (void)out_size;

    const int NB = (N_NODES + 255) / 256;
    const int GB = (N_NODES + 63) / 64;

    hipMemsetAsync(cnt, 0, (size_t)N_NODES * 4, stream);
    count_deg<<<(ET + 255) / 256, 256, 0, stream>>>(ei, cnt);
    scan_partial<<<NB, 256, 0, stream>>>(cnt, offs, bsums);
    scan_root<<<1, 256, 0, stream>>>(bsums, boffs, NB);
    scan_add<<<NB, 256, 0, stream>>>(offs, boffs, bsums, bcur, NB);
    scatter_pairs<<<(ET + 255) / 256, 256, 0, stream>>>(ei, bcur, pairs);
    group_bucket<<<NBUCK, 256, 0, stream>>>(pairs, offs, ssrc);

    prep_inputs<<<CAST_B + 2 * PACK_B, 256, 0, stream>>>(x, xb, W0, W0p, W1, W1p);

    gemm_attn<<<GB, 256, 0, stream>>>(xb, W0p, as0, ad0, Hb, asn, adn, N_NODES);
    aggregate<<<(N_NODES + 3) / 4, 256, 0, stream>>>(Hb, asn, adn, offs, ssrc,
                                                     b0, g0, bb0, rm0, rv0, Xb);
    gemm_attn<<<GB, 256, 0, stream>>>(Xb, W1p, as1, ad1, Hb, asn, adn, N_NODES);
    aggregate<<<(N_NODES + 3) / 4, 256, 0, stream>>>(Hb, asn, adn, offs, ssrc,
                                                     b1, g1, bb1, rm1, rv1, Xb);
    gemm2_fused<<<NB, 256, 0, stream>>>(Xb, W2, as2, ad2, h2, as2n, ad2n);
    aggregate2<<<(N_NODES + 3) / 4, 256, 0, stream>>>(h2, as2n, ad2n, offs, ssrc, b2, out);
}

// Round 7
// 329.044 us; speedup vs baseline: 1.3539x; 1.3539x over previous
//
#include <hip/hip_runtime.h>
#include <math.h>

#define N_NODES 50000
#define N_EDGES 800000
#define ET (N_EDGES + N_NODES)   // with self-loops
#define FDIM 128
#define HEADS 4
#define HID 32
#define NCLS 8
#define NEG 0.2f
#define EPS_BN 1e-5f

#define BSH 8                                   // 256 nodes per bucket
#define NBUCK ((N_NODES + 255) >> BSH)          // 196
#define EPB 4096                                // edges per partition block

typedef __attribute__((ext_vector_type(8))) short short8;
typedef __attribute__((ext_vector_type(4))) float f32x4;

__device__ __forceinline__ float lrelu(float e) { return e > 0.f ? e : NEG * e; }
__device__ __forceinline__ float bflo(unsigned u) { return __uint_as_float(u << 16); }
__device__ __forceinline__ float bfhi(unsigned u) { return __uint_as_float(u & 0xffff0000u); }
__device__ __forceinline__ unsigned f2bf(float f) {           // RNE round to bf16 bits
    unsigned b = __float_as_uint(f);
    return (b + 0x7fffu + ((b >> 16) & 1u)) >> 16;
}

// ---------------- graph prep ----------------

__global__ void count_deg(const int* __restrict__ ei, int* __restrict__ cnt) {
    int e = blockIdx.x * blockDim.x + threadIdx.x;
    if (e >= ET) return;
    int d = (e < N_EDGES) ? ei[N_EDGES + e] : (e - N_EDGES);
    atomicAdd(&cnt[d], 1);
}

__global__ void scan_partial(const int* __restrict__ cnt, int* __restrict__ offs,
                             int* __restrict__ bsums) {
    __shared__ int s[256];
    int tid = threadIdx.x;
    int i = blockIdx.x * 256 + tid;
    int v = (i < N_NODES) ? cnt[i] : 0;
    s[tid] = v;
    __syncthreads();
    for (int off = 1; off < 256; off <<= 1) {
        int x = (tid >= off) ? s[tid - off] : 0;
        __syncthreads();
        s[tid] += x;
        __syncthreads();
    }
    if (i < N_NODES) offs[i] = s[tid] - v;
    if (tid == 255) bsums[blockIdx.x] = s[255];
}

__global__ void scan_root(const int* __restrict__ bsums, int* __restrict__ boffs, int nb) {
    __shared__ int s[256];
    int tid = threadIdx.x;
    int v = (tid < nb) ? bsums[tid] : 0;
    s[tid] = v;
    __syncthreads();
    for (int off = 1; off < 256; off <<= 1) {
        int x = (tid >= off) ? s[tid - off] : 0;
        __syncthreads();
        s[tid] += x;
        __syncthreads();
    }
    boffs[tid] = s[tid] - v;
}

// offs finalize + bucket-cursor init (bcur[b] = offs[b<<BSH])
__global__ void scan_add(int* __restrict__ offs, const int* __restrict__ boffs,
                         const int* __restrict__ bsums, int* __restrict__ bcur, int nb) {
    int i = blockIdx.x * 256 + threadIdx.x;
    if (i < N_NODES) {
        int v = offs[i] + boffs[blockIdx.x];
        offs[i] = v;
        if ((i & ((1 << BSH) - 1)) == 0) bcur[i >> BSH] = v;
    }
    if (i == 0) offs[N_NODES] = boffs[nb - 1] + bsums[nb - 1];
}

// pass A: LDS-histogram radix partition into bucket regions.
// One global returning atomic per (block, nonempty bucket); writes are ~bucket-run
// contiguous (avg 21 pairs = 168 B per run).
__global__ __launch_bounds__(256) void partition_pairs(const int* __restrict__ ei,
                                                       int* __restrict__ bcur,
                                                       int2* __restrict__ pairs) {
    __shared__ unsigned hist[NBUCK];
    __shared__ unsigned base[NBUCK];
    int tid = threadIdx.x;
    int e0 = blockIdx.x * EPB;
    for (int i = tid; i < NBUCK; i += 256) hist[i] = 0;
    __syncthreads();
    #pragma unroll
    for (int k = 0; k < EPB / 256; k++) {
        int e = e0 + k * 256 + tid;
        if (e < ET) {
            int d = (e < N_EDGES) ? ei[N_EDGES + e] : (e - N_EDGES);
            atomicAdd(&hist[d >> BSH], 1u);
        }
    }
    __syncthreads();
    for (int i = tid; i < NBUCK; i += 256) {
        unsigned h = hist[i];
        base[i] = h ? (unsigned)atomicAdd(&bcur[i], (int)h) : 0u;
        hist[i] = 0;
    }
    __syncthreads();
    #pragma unroll
    for (int k = 0; k < EPB / 256; k++) {
        int e = e0 + k * 256 + tid;
        if (e < ET) {
            int s, d;
            if (e < N_EDGES) { s = ei[e]; d = ei[N_EDGES + e]; }
            else             { s = d = e - N_EDGES; }
            int b = d >> BSH;
            unsigned lpos = atomicAdd(&hist[b], 1u);
            pairs[base[b] + lpos] = make_int2(s, d);
        }
    }
}

// pass B: within each bucket region, group by node via LDS cursors
__global__ __launch_bounds__(256) void group_bucket(const int2* __restrict__ pairs,
                                                    const int* __restrict__ offs,
                                                    int* __restrict__ ssrc) {
    __shared__ int lcur[1 << BSH];
    int b = blockIdx.x, tid = threadIdx.x;
    int n0 = b << BSH;
    int base = offs[n0];
    int nend = n0 + (1 << BSH); if (nend > N_NODES) nend = N_NODES;
    int regionEnd = offs[nend];
    lcur[tid] = (n0 + tid < N_NODES) ? (offs[n0 + tid] - base) : 0;
    __syncthreads();
    for (int i = base + tid; i < regionEnd; i += 256) {
        int2 p = pairs[i];
        int pos = atomicAdd(&lcur[p.y & ((1 << BSH) - 1)], 1);
        ssrc[base + pos] = p.x;
    }
}

// ---------------- fused input prep: x->bf16 cast + W0/W1 fragment packing ----------------

#define CAST_B 3125   // 50000*128/8/256
#define PACK_B 64     // 16384/256

__global__ void prep_inputs(const float* __restrict__ x, unsigned short* __restrict__ xb,
                            const float* __restrict__ W0, unsigned short* __restrict__ W0p,
                            const float* __restrict__ W1, unsigned short* __restrict__ W1p) {
    int b = blockIdx.x, tid = threadIdx.x;
    if (b < CAST_B) {
        int i = b * 256 + tid;
        const float4* p = (const float4*)x + (size_t)i * 2;
        float4 a = p[0], c = p[1];
        uint4 o;
        o.x = f2bf(a.x) | (f2bf(a.y) << 16);
        o.y = f2bf(a.z) | (f2bf(a.w) << 16);
        o.z = f2bf(c.x) | (f2bf(c.y) << 16);
        o.w = f2bf(c.z) | (f2bf(c.w) << 16);
        ((uint4*)xb)[i] = o;
    } else {
        int pb = b - CAST_B;
        const float* W = (pb < PACK_B) ? W0 : W1;
        unsigned short* Wp = (pb < PACK_B) ? W0p : W1p;
        int o = (pb & (PACK_B - 1)) * 256 + tid;
        int j = o & 7, lane = (o >> 3) & 63, kc = (o >> 9) & 3, t = o >> 11;
        int k = kc * 32 + ((lane >> 4) << 3) + j;
        int n = t * 16 + (lane & 15);
        Wp[o] = (unsigned short)f2bf(W[k * 128 + n]);
    }
}

// ------- fused MFMA GEMM (M x 128 @ 128 x 128) + bf16 h-store + attn coeffs -------

__global__ __launch_bounds__(256) void gemm_attn(
        const unsigned short* __restrict__ Ab, const unsigned short* __restrict__ Wp,
        const float* __restrict__ att_s, const float* __restrict__ att_d,
        unsigned short* __restrict__ Hb, float* __restrict__ asn, float* __restrict__ adn,
        int M) {
    __shared__ float tiles[64 * 132];
    int tid = threadIdx.x;
    int wv = tid >> 6, lane = tid & 63;
    int base = blockIdx.x * 64;
    int mrow = base + wv * 16 + (lane & 15);
    if (mrow >= M) mrow = M - 1;
    int koff = (lane >> 4) * 8;

    f32x4 acc[8];
    #pragma unroll
    for (int t = 0; t < 8; t++) acc[t] = (f32x4){0.f, 0.f, 0.f, 0.f};

    #pragma unroll
    for (int kc = 0; kc < 4; kc++) {
        short8 a = *(const short8*)(Ab + (size_t)mrow * 128 + kc * 32 + koff);
        #pragma unroll
        for (int t = 0; t < 8; t++) {
            short8 b = *(const short8*)(Wp + (((t * 4 + kc) * 64 + lane) << 3));
            acc[t] = __builtin_amdgcn_mfma_f32_16x16x32_bf16(a, b, acc[t], 0, 0, 0);
        }
    }

    int rbase = wv * 16 + (lane >> 4) * 4;
    int col = lane & 15;
    #pragma unroll
    for (int t = 0; t < 8; t++)
        #pragma unroll
        for (int r = 0; r < 4; r++)
            tiles[(rbase + r) * 132 + t * 16 + col] = acc[t][r];
    __syncthreads();

    #pragma unroll
    for (int it = 0; it < 4; it++) {
        int u = tid + it * 256;
        int rl = u >> 4, cg = u & 15;
        int row = base + rl;
        if (row < M) {
            const float* p = tiles + rl * 132 + cg * 8;
            float4 v0 = *(const float4*)(p);
            float4 v1 = *(const float4*)(p + 4);
            uint4 o;
            o.x = f2bf(v0.x) | (f2bf(v0.y) << 16);
            o.y = f2bf(v0.z) | (f2bf(v0.w) << 16);
            o.z = f2bf(v1.x) | (f2bf(v1.y) << 16);
            o.w = f2bf(v1.z) | (f2bf(v1.w) << 16);
            *(uint4*)(Hb + (size_t)row * 128 + cg * 8) = o;
        }
    }

    {
        int rl = tid >> 2, hd = tid & 3;
        int row = base + rl;
        if (row < M) {
            const float* hrow = tiles + rl * 132 + hd * 32;
            const float* as = att_s + hd * 32;
            const float* ad = att_d + hd * 32;
            float ps = 0.f, pd = 0.f;
            #pragma unroll
            for (int i = 0; i < 8; i++) {
                float4 hv = *(const float4*)(hrow + i * 4);
                float4 sv = *(const float4*)(as + i * 4);
                float4 dv = *(const float4*)(ad + i * 4);
                ps += hv.x * sv.x + hv.y * sv.y + hv.z * sv.z + hv.w * sv.w;
                pd += hv.x * dv.x + hv.y * dv.y + hv.z * dv.z + hv.w * dv.w;
            }
            asn[row * 4 + hd] = ps;
            adn[row * 4 + hd] = pd;
        }
    }
}

// ------- aggregation + bias + BN + ELU (layers 0,1): one wave/node, channel-parallel -------

__global__ __launch_bounds__(256) void aggregate(
        const unsigned short* __restrict__ hb, const float* __restrict__ asn,
        const float* __restrict__ adn, const int* __restrict__ offs,
        const int* __restrict__ ssrc, const float* __restrict__ bias,
        const float* __restrict__ gamma, const float* __restrict__ beta,
        const float* __restrict__ rmean, const float* __restrict__ rvar,
        unsigned short* __restrict__ outb) {
    __shared__ int2 sPair[4][4][72];   // [wave][head][slot]; stride 72 -> heads offset 16 banks
    int wv = threadIdx.x >> 6;
    int node = blockIdx.x * 4 + wv;
    if (node >= N_NODES) return;
    int lane = threadIdx.x & 63;
    int hd = lane >> 4;
    int beg = offs[node], deg = offs[node + 1] - beg;
    float4 ad4 = *(const float4*)(adn + node * 4);

    if (lane < 32) sPair[wv][lane >> 3][64 + (lane & 7)] = make_int2(0, 0);

    int s0 = 0;
    float4 e4 = make_float4(-1e30f, -1e30f, -1e30f, -1e30f);
    if (lane < deg) {
        s0 = ssrc[beg + lane];
        float4 a = *(const float4*)(asn + s0 * 4);
        e4.x = lrelu(a.x + ad4.x); e4.y = lrelu(a.y + ad4.y);
        e4.z = lrelu(a.z + ad4.z); e4.w = lrelu(a.w + ad4.w);
    }
    float4 m4 = e4;
    for (int base = 64; base < deg; base += 64) {   // rare
        int j = base + lane;
        if (j < deg) {
            int s = ssrc[beg + j];
            float4 a = *(const float4*)(asn + s * 4);
            m4.x = fmaxf(m4.x, lrelu(a.x + ad4.x));
            m4.y = fmaxf(m4.y, lrelu(a.y + ad4.y));
            m4.z = fmaxf(m4.z, lrelu(a.z + ad4.z));
            m4.w = fmaxf(m4.w, lrelu(a.w + ad4.w));
        }
    }
    #pragma unroll
    for (int off = 32; off; off >>= 1) {
        m4.x = fmaxf(m4.x, __shfl_xor(m4.x, off));
        m4.y = fmaxf(m4.y, __shfl_xor(m4.y, off));
        m4.z = fmaxf(m4.z, __shfl_xor(m4.z, off));
        m4.w = fmaxf(m4.w, __shfl_xor(m4.w, off));
    }

    float4 den4 = make_float4(0.f, 0.f, 0.f, 0.f);
    float acc0 = 0.f, acc1 = 0.f;
    const unsigned short* hlane = hb + 2 * lane;
    const int2* pp = &sPair[wv][hd][0];

    auto phaseC = [&](int cnt) {
        int bound = (cnt + 7) & ~7;
        for (int i = 0; i < bound; i += 8) {
            int2 p0 = pp[i],     p1 = pp[i + 1], p2 = pp[i + 2], p3 = pp[i + 3];
            int2 p4 = pp[i + 4], p5 = pp[i + 5], p6 = pp[i + 6], p7 = pp[i + 7];
            unsigned u0 = *(const unsigned*)(hlane + (((unsigned)p0.x) << 7));
            unsigned u1 = *(const unsigned*)(hlane + (((unsigned)p1.x) << 7));
            unsigned u2 = *(const unsigned*)(hlane + (((unsigned)p2.x) << 7));
            unsigned u3 = *(const unsigned*)(hlane + (((unsigned)p3.x) << 7));
            unsigned u4 = *(const unsigned*)(hlane + (((unsigned)p4.x) << 7));
            unsigned u5 = *(const unsigned*)(hlane + (((unsigned)p5.x) << 7));
            unsigned u6 = *(const unsigned*)(hlane + (((unsigned)p6.x) << 7));
            unsigned u7 = *(const unsigned*)(hlane + (((unsigned)p7.x) << 7));
            acc0 += __int_as_float(p0.y) * bflo(u0); acc1 += __int_as_float(p0.y) * bfhi(u0);
            acc0 += __int_as_float(p1.y) * bflo(u1); acc1 += __int_as_float(p1.y) * bfhi(u1);
            acc0 += __int_as_float(p2.y) * bflo(u2); acc1 += __int_as_float(p2.y) * bfhi(u2);
            acc0 += __int_as_float(p3.y) * bflo(u3); acc1 += __int_as_float(p3.y) * bfhi(u3);
            acc0 += __int_as_float(p4.y) * bflo(u4); acc1 += __int_as_float(p4.y) * bfhi(u4);
            acc0 += __int_as_float(p5.y) * bflo(u5); acc1 += __int_as_float(p5.y) * bfhi(u5);
            acc0 += __int_as_float(p6.y) * bflo(u6); acc1 += __int_as_float(p6.y) * bfhi(u6);
            acc0 += __int_as_float(p7.y) * bflo(u7); acc1 += __int_as_float(p7.y) * bfhi(u7);
        }
    };

    {
        float4 w4 = make_float4(0.f, 0.f, 0.f, 0.f);
        if (lane < deg) {
            w4.x = __expf(e4.x - m4.x); w4.y = __expf(e4.y - m4.y);
            w4.z = __expf(e4.z - m4.z); w4.w = __expf(e4.w - m4.w);
            den4.x += w4.x; den4.y += w4.y; den4.z += w4.z; den4.w += w4.w;
        }
        sPair[wv][0][lane] = make_int2(s0, __float_as_int(w4.x));
        sPair[wv][1][lane] = make_int2(s0, __float_as_int(w4.y));
        sPair[wv][2][lane] = make_int2(s0, __float_as_int(w4.z));
        sPair[wv][3][lane] = make_int2(s0, __float_as_int(w4.w));
        phaseC(deg < 64 ? deg : 64);
    }
    for (int base = 64; base < deg; base += 64) {
        int j = base + lane;
        int s = 0;
        float4 w4 = make_float4(0.f, 0.f, 0.f, 0.f);
        if (j < deg) {
            s = ssrc[beg + j];
            float4 a = *(const float4*)(asn + s * 4);
            w4.x = __expf(lrelu(a.x + ad4.x) - m4.x);
            w4.y = __expf(lrelu(a.y + ad4.y) - m4.y);
            w4.z = __expf(lrelu(a.z + ad4.z) - m4.z);
            w4.w = __expf(lrelu(a.w + ad4.w) - m4.w);
            den4.x += w4.x; den4.y += w4.y; den4.z += w4.z; den4.w += w4.w;
        }
        sPair[wv][0][lane] = make_int2(s, __float_as_int(w4.x));
        sPair[wv][1][lane] = make_int2(s, __float_as_int(w4.y));
        sPair[wv][2][lane] = make_int2(s, __float_as_int(w4.z));
        sPair[wv][3][lane] = make_int2(s, __float_as_int(w4.w));
        int cnt = deg - base; if (cnt > 64) cnt = 64;
        phaseC(cnt);
    }

    #pragma unroll
    for (int off = 32; off; off >>= 1) {
        den4.x += __shfl_xor(den4.x, off);
        den4.y += __shfl_xor(den4.y, off);
        den4.z += __shfl_xor(den4.z, off);
        den4.w += __shfl_xor(den4.w, off);
    }
    float den = (hd & 2) ? ((hd & 1) ? den4.w : den4.z)
                         : ((hd & 1) ? den4.y : den4.x);
    float inv = 1.f / (den + 1e-16f);

    int c0 = lane * 2;
    float2 bi = *(const float2*)(bias + c0);
    float2 gm = *(const float2*)(gamma + c0);
    float2 bt = *(const float2*)(beta + c0);
    float2 rm = *(const float2*)(rmean + c0);
    float2 rv = *(const float2*)(rvar + c0);
    float o0 = acc0 * inv + bi.x;
    float o1 = acc1 * inv + bi.y;
    o0 = (o0 - rm.x) * rsqrtf(rv.x + EPS_BN) * gm.x + bt.x;
    o1 = (o1 - rm.y) * rsqrtf(rv.y + EPS_BN) * gm.y + bt.y;
    o0 = (o0 > 0.f) ? o0 : expm1f(o0);
    o1 = (o1 > 0.f) ? o1 : expm1f(o1);
    *(unsigned*)(outb + (size_t)node * 128 + c0) = f2bf(o0) | (f2bf(o1) << 16);
}

// ---------------- layer 2: fused GEMM(128->8) + attn coeffs (bf16 input) ----------------

__global__ __launch_bounds__(256) void gemm2_fused(
        const unsigned short* __restrict__ xb, const float* __restrict__ W2,
        const float* __restrict__ as2, const float* __restrict__ ad2,
        float* __restrict__ h2, float* __restrict__ asn, float* __restrict__ adn) {
    __shared__ float sW[128 * 8];
    __shared__ float sas[8], sad[8];
    int tid = threadIdx.x;
    for (int i = tid; i < 1024; i += 256) sW[i] = W2[i];
    if (tid < 8) { sas[tid] = as2[tid]; sad[tid] = ad2[tid]; }
    __syncthreads();
    int node = blockIdx.x * 256 + tid;
    if (node >= N_NODES) return;
    const uint4* xr = (const uint4*)(xb + (size_t)node * 128);
    float acc[8];
    #pragma unroll
    for (int c = 0; c < 8; c++) acc[c] = 0.f;
    for (int k8 = 0; k8 < 16; k8++) {
        uint4 u = xr[k8];
        float f[8] = { bflo(u.x), bfhi(u.x), bflo(u.y), bfhi(u.y),
                       bflo(u.z), bfhi(u.z), bflo(u.w), bfhi(u.w) };
        int kb = k8 * 8;
        #pragma unroll
        for (int q = 0; q < 8; q++)
            #pragma unroll
            for (int c = 0; c < 8; c++)
                acc[c] += f[q] * sW[(kb + q) * 8 + c];
    }
    float ps = 0.f, pd = 0.f;
    #pragma unroll
    for (int c = 0; c < 8; c++) {
        h2[(size_t)node * 8 + c] = acc[c];
        ps += acc[c] * sas[c];
        pd += acc[c] * sad[c];
    }
    asn[node] = ps;
    adn[node] = pd;
}

// ------- layer 2 aggregation + bias + log_softmax: one wave/node -------

__global__ __launch_bounds__(256) void aggregate2(
        const float* __restrict__ h2, const float* __restrict__ asn,
        const float* __restrict__ adn, const int* __restrict__ offs,
        const int* __restrict__ ssrc, const float* __restrict__ b2,
        float* __restrict__ out) {
    __shared__ int2 sPair[4][64];
    int wv = threadIdx.x >> 6;
    int node = blockIdx.x * 4 + wv;
    if (node >= N_NODES) return;
    int lane = threadIdx.x & 63;
    int g = lane >> 3, c = lane & 7;
    int beg = offs[node], end = offs[node + 1];
    int deg = end - beg;
    float adv = adn[node];

    int s0 = 0;
    float e0v = -1e30f;
    if (lane < deg) {
        s0 = ssrc[beg + lane];
        e0v = lrelu(asn[s0] + adv);
    }
    float m = e0v;
    for (int base = 64; base < deg; base += 64) {
        int j = base + lane;
        if (j < deg) m = fmaxf(m, lrelu(asn[ssrc[beg + j]] + adv));
    }
    #pragma unroll
    for (int off = 32; off; off >>= 1) m = fmaxf(m, __shfl_xor(m, off));

    float den = 0.f, acc = 0.f;
    auto phaseC = [&](int cnt) {
        int nIt = (cnt + 15) >> 4;
        const int2* pp = &sPair[wv][0];
        for (int i = 0; i < nIt; i++) {
            int e = i * 16 + g;
            int2 p0 = pp[e];
            int2 p1 = pp[e + 8];
            acc += __int_as_float(p0.y) * h2[(((unsigned)p0.x) << 3) + c];
            acc += __int_as_float(p1.y) * h2[(((unsigned)p1.x) << 3) + c];
        }
    };

    {
        float w = 0.f;
        if (lane < deg) { w = __expf(e0v - m); den += w; }
        sPair[wv][lane] = make_int2(s0, __float_as_int(w));
        int cnt = deg < 64 ? deg : 64;
        phaseC(cnt);
    }
    for (int base = 64; base < deg; base += 64) {
        int j = base + lane;
        int s = 0; float w = 0.f;
        if (j < deg) {
            s = ssrc[beg + j];
            w = __expf(lrelu(asn[s] + adv) - m);
            den += w;
        }
        sPair[wv][lane] = make_int2(s, __float_as_int(w));
        int cnt = deg - base; if (cnt > 64) cnt = 64;
        phaseC(cnt);
    }

    acc += __shfl_xor(acc, 8); acc += __shfl_xor(acc, 16); acc += __shfl_xor(acc, 32);
    #pragma unroll
    for (int off = 32; off; off >>= 1) den += __shfl_xor(den, off);

    float o = acc / (den + 1e-16f) + b2[c];
    float mx = o;
    mx = fmaxf(mx, __shfl_xor(mx, 1));
    mx = fmaxf(mx, __shfl_xor(mx, 2));
    mx = fmaxf(mx, __shfl_xor(mx, 4));
    float ex = __expf(o - mx);
    float sm = ex;
    sm += __shfl_xor(sm, 1); sm += __shfl_xor(sm, 2); sm += __shfl_xor(sm, 4);
    if (g == 0) out[(size_t)node * 8 + c] = o - mx - logf(sm);
}

// ---------------- launch ----------------

extern "C" void kernel_launch(void* const* d_in, const int* in_sizes, int n_in,
                              void* d_out, int out_size, void* d_ws, size_t ws_size,
                              hipStream_t stream) {
    const float* x   = (const float*)d_in[0];
    const int*   ei  = (const int*)d_in[1];
    const float* W0  = (const float*)d_in[2];
    const float* as0 = (const float*)d_in[3];
    const float* ad0 = (const float*)d_in[4];
    const float* b0  = (const float*)d_in[5];
    const float* g0  = (const float*)d_in[6];
    const float* bb0 = (const float*)d_in[7];
    const float* rm0 = (const float*)d_in[8];
    const float* rv0 = (const float*)d_in[9];
    const float* W1  = (const float*)d_in[10];
    const float* as1 = (const float*)d_in[11];
    const float* ad1 = (const float*)d_in[12];
    const float* b1  = (const float*)d_in[13];
    const float* g1  = (const float*)d_in[14];
    const float* bb1 = (const float*)d_in[15];
    const float* rm1 = (const float*)d_in[16];
    const float* rv1 = (const float*)d_in[17];
    const float* W2  = (const float*)d_in[18];
    const float* as2 = (const float*)d_in[19];
    const float* ad2 = (const float*)d_in[20];
    const float* b2  = (const float*)d_in[21];
    float* out = (float*)d_out;

    char* w = (char*)d_ws;
    size_t off = 0;
    auto carve = [&](size_t bytes) {
        void* p = w + off;
        off += (bytes + 255) & ~(size_t)255;
        return p;
    };
    unsigned short* xb   = (unsigned short*)carve((size_t)N_NODES * 128 * 2);
    unsigned short* Hb   = (unsigned short*)carve((size_t)N_NODES * 128 * 2);
    unsigned short* Xb   = (unsigned short*)carve((size_t)N_NODES * 128 * 2);
    unsigned short* W0p  = (unsigned short*)carve(16384 * 2);
    unsigned short* W1p  = (unsigned short*)carve(16384 * 2);
    int*   cnt    = (int*)carve((size_t)N_NODES * 4);
    int*   offs   = (int*)carve((size_t)(N_NODES + 1) * 4);
    int*   bcur   = (int*)carve((size_t)NBUCK * 4);
    int*   bsums  = (int*)carve(1024);
    int*   boffs  = (int*)carve(1024);
    int*   ssrc   = (int*)carve((size_t)ET * 4);
    int2*  pairs  = (int2*)carve((size_t)ET * 8);
    float* asn    = (float*)carve((size_t)N_NODES * 4 * 4);
    float* adn    = (float*)carve((size_t)N_NODES * 4 * 4);
    float* h2     = (float*)carve((size_t)N_NODES * 8 * 4);
    float* as2n   = (float*)carve((size_t)N_NODES * 4);
    float* ad2n   = (float*)carve((size_t)N_NODES * 4);
    (void)ws_size; (void)in_sizes; (void)n_in; (void)out_size;

    const int NB = (N_NODES + 255) / 256;
    const int GB = (N_NODES + 63) / 64;

    hipMemsetAsync(cnt, 0, (size_t)N_NODES * 4, stream);
    count_deg<<<(ET + 255) / 256, 256, 0, stream>>>(ei, cnt);
    scan_partial<<<NB, 256, 0, stream>>>(cnt, offs, bsums);
    scan_root<<<1, 256, 0, stream>>>(bsums, boffs, NB);
    scan_add<<<NB, 256, 0, stream>>>(offs, boffs, bsums, bcur, NB);
    partition_pairs<<<(ET + EPB - 1) / EPB, 256, 0, stream>>>(ei, bcur, pairs);
    group_bucket<<<NBUCK, 256, 0, stream>>>(pairs, offs, ssrc);

    prep_inputs<<<CAST_B + 2 * PACK_B, 256, 0, stream>>>(x, xb, W0, W0p, W1, W1p);

    gemm_attn<<<GB, 256, 0, stream>>>(xb, W0p, as0, ad0, Hb, asn, adn, N_NODES);
    aggregate<<<(N_NODES + 3) / 4, 256, 0, stream>>>(Hb, asn, adn, offs, ssrc,
                                                     b0, g0, bb0, rm0, rv0, Xb);
    gemm_attn<<<GB, 256, 0, stream>>>(Xb, W1p, as1, ad1, Hb, asn, adn, N_NODES);
    aggregate<<<(N_NODES + 3) / 4, 256, 0, stream>>>(Hb, asn, adn, offs, ssrc,
                                                     b1, g1, bb1, rm1, rv1, Xb);
    gemm2_fused<<<NB, 256, 0, stream>>>(Xb, W2, as2, ad2, h2, as2n, ad2n);
    aggregate2<<<(N_NODES + 3) / 4, 256, 0, stream>>>(h2, as2n, ad2n, offs, ssrc, b2, out);
}

// Round 8
// 289.788 us; speedup vs baseline: 1.5374x; 1.1355x over previous
//
#include <hip/hip_runtime.h>
#include <math.h>

#define N_NODES 50000
#define N_EDGES 800000
#define ET (N_EDGES + N_NODES)   // with self-loops
#define FDIM 128
#define HEADS 4
#define HID 32
#define NCLS 8
#define NEG 0.2f
#define EPS_BN 1e-5f

#define BSH 8                                   // 256 nodes per bucket
#define NBUCK ((N_NODES + 255) >> BSH)          // 196
#define EPB 4096                                // edges per partition block

typedef __attribute__((ext_vector_type(8))) short short8;
typedef __attribute__((ext_vector_type(4))) float f32x4;

__device__ __forceinline__ float lrelu(float e) { return e > 0.f ? e : NEG * e; }
__device__ __forceinline__ float bflo(unsigned u) { return __uint_as_float(u << 16); }
__device__ __forceinline__ float bfhi(unsigned u) { return __uint_as_float(u & 0xffff0000u); }
__device__ __forceinline__ unsigned f2bf(float f) {           // RNE round to bf16 bits
    unsigned b = __float_as_uint(f);
    return (b + 0x7fffu + ((b >> 16) & 1u)) >> 16;
}

// ---------------- graph prep (bucket-granularity; no per-node global atomics) ----------------

// bucket histogram via LDS, one global atomic per (block, bucket)
__global__ __launch_bounds__(256) void bucket_hist(const int* __restrict__ ei,
                                                   int* __restrict__ bhist) {
    __shared__ unsigned h[NBUCK];
    int tid = threadIdx.x;
    int e0 = blockIdx.x * EPB;
    for (int i = tid; i < NBUCK; i += 256) h[i] = 0;
    __syncthreads();
    #pragma unroll
    for (int k = 0; k < EPB / 256; k++) {
        int e = e0 + k * 256 + tid;
        if (e < ET) {
            int d = (e < N_EDGES) ? ei[N_EDGES + e] : (e - N_EDGES);
            atomicAdd(&h[d >> BSH], 1u);
        }
    }
    __syncthreads();
    for (int i = tid; i < NBUCK; i += 256)
        if (h[i]) atomicAdd(&bhist[i], (int)h[i]);
}

// single-block exclusive scan of 196 bucket counts -> boffs, bcur; offs[N] = ET
__global__ __launch_bounds__(256) void scan_buckets(const int* __restrict__ bhist,
                                                    int* __restrict__ boffs,
                                                    int* __restrict__ bcur,
                                                    int* __restrict__ offs) {
    __shared__ int s[256];
    int tid = threadIdx.x;
    int v = (tid < NBUCK) ? bhist[tid] : 0;
    s[tid] = v;
    __syncthreads();
    for (int off = 1; off < 256; off <<= 1) {
        int x = (tid >= off) ? s[tid - off] : 0;
        __syncthreads();
        s[tid] += x;
        __syncthreads();
    }
    int excl = s[tid] - v;
    if (tid < NBUCK) { boffs[tid] = excl; bcur[tid] = excl; }
    if (tid == 0) { boffs[NBUCK] = ET; offs[N_NODES] = ET; }
}

// pass A: LDS-histogram radix partition into bucket regions
__global__ __launch_bounds__(256) void partition_pairs(const int* __restrict__ ei,
                                                       int* __restrict__ bcur,
                                                       int2* __restrict__ pairs) {
    __shared__ unsigned hist[NBUCK];
    __shared__ unsigned base[NBUCK];
    int tid = threadIdx.x;
    int e0 = blockIdx.x * EPB;
    for (int i = tid; i < NBUCK; i += 256) hist[i] = 0;
    __syncthreads();
    #pragma unroll
    for (int k = 0; k < EPB / 256; k++) {
        int e = e0 + k * 256 + tid;
        if (e < ET) {
            int d = (e < N_EDGES) ? ei[N_EDGES + e] : (e - N_EDGES);
            atomicAdd(&hist[d >> BSH], 1u);
        }
    }
    __syncthreads();
    for (int i = tid; i < NBUCK; i += 256) {
        unsigned h = hist[i];
        base[i] = h ? (unsigned)atomicAdd(&bcur[i], (int)h) : 0u;
        hist[i] = 0;
    }
    __syncthreads();
    #pragma unroll
    for (int k = 0; k < EPB / 256; k++) {
        int e = e0 + k * 256 + tid;
        if (e < ET) {
            int s, d;
            if (e < N_EDGES) { s = ei[e]; d = ei[N_EDGES + e]; }
            else             { s = d = e - N_EDGES; }
            int b = d >> BSH;
            unsigned lpos = atomicAdd(&hist[b], 1u);
            pairs[base[b] + lpos] = make_int2(s, d);
        }
    }
}

// pass B: per bucket, derive per-node offsets in LDS (count + scan), write offs
// coalesced, then regroup pairs -> ssrc via LDS cursors.
__global__ __launch_bounds__(256) void group_bucket(const int2* __restrict__ pairs,
                                                    const int* __restrict__ boffs,
                                                    int* __restrict__ offs,
                                                    int* __restrict__ ssrc) {
    __shared__ int cnt[256];
    __shared__ int pfx[256];
    int b = blockIdx.x, tid = threadIdx.x;
    int n0 = b << BSH;
    int base = boffs[b], end = boffs[b + 1];
    cnt[tid] = 0;
    __syncthreads();
    for (int i = base + tid; i < end; i += 256)
        atomicAdd(&cnt[pairs[i].y & 255], 1);
    __syncthreads();
    int v = cnt[tid];
    pfx[tid] = v;
    __syncthreads();
    for (int off = 1; off < 256; off <<= 1) {
        int x = (tid >= off) ? pfx[tid - off] : 0;
        __syncthreads();
        pfx[tid] += x;
        __syncthreads();
    }
    int excl = pfx[tid] - v;
    if (n0 + tid < N_NODES) offs[n0 + tid] = base + excl;
    cnt[tid] = excl;                 // reuse as cursor
    __syncthreads();
    for (int i = base + tid; i < end; i += 256) {
        int2 p = pairs[i];
        int pos = atomicAdd(&cnt[p.y & 255], 1);
        ssrc[base + pos] = p.x;
    }
}

// ---------------- fused input prep: x->bf16 cast + W0/W1 fragment packing ----------------

#define CAST_B 3125   // 50000*128/8/256
#define PACK_B 64     // 16384/256

__global__ void prep_inputs(const float* __restrict__ x, unsigned short* __restrict__ xb,
                            const float* __restrict__ W0, unsigned short* __restrict__ W0p,
                            const float* __restrict__ W1, unsigned short* __restrict__ W1p) {
    int b = blockIdx.x, tid = threadIdx.x;
    if (b < CAST_B) {
        int i = b * 256 + tid;
        const float4* p = (const float4*)x + (size_t)i * 2;
        float4 a = p[0], c = p[1];
        uint4 o;
        o.x = f2bf(a.x) | (f2bf(a.y) << 16);
        o.y = f2bf(a.z) | (f2bf(a.w) << 16);
        o.z = f2bf(c.x) | (f2bf(c.y) << 16);
        o.w = f2bf(c.z) | (f2bf(c.w) << 16);
        ((uint4*)xb)[i] = o;
    } else {
        int pb = b - CAST_B;
        const float* W = (pb < PACK_B) ? W0 : W1;
        unsigned short* Wp = (pb < PACK_B) ? W0p : W1p;
        int o = (pb & (PACK_B - 1)) * 256 + tid;
        int j = o & 7, lane = (o >> 3) & 63, kc = (o >> 9) & 3, t = o >> 11;
        int k = kc * 32 + ((lane >> 4) << 3) + j;
        int n = t * 16 + (lane & 15);
        Wp[o] = (unsigned short)f2bf(W[k * 128 + n]);
    }
}

// ------- fused MFMA GEMM (M x 128 @ 128 x 128) + bf16 h-store + attn coeffs -------

__global__ __launch_bounds__(256) void gemm_attn(
        const unsigned short* __restrict__ Ab, const unsigned short* __restrict__ Wp,
        const float* __restrict__ att_s, const float* __restrict__ att_d,
        unsigned short* __restrict__ Hb, float* __restrict__ asn, float* __restrict__ adn,
        int M) {
    __shared__ float tiles[64 * 132];
    int tid = threadIdx.x;
    int wv = tid >> 6, lane = tid & 63;
    int base = blockIdx.x * 64;
    int mrow = base + wv * 16 + (lane & 15);
    if (mrow >= M) mrow = M - 1;
    int koff = (lane >> 4) * 8;

    f32x4 acc[8];
    #pragma unroll
    for (int t = 0; t < 8; t++) acc[t] = (f32x4){0.f, 0.f, 0.f, 0.f};

    #pragma unroll
    for (int kc = 0; kc < 4; kc++) {
        short8 a = *(const short8*)(Ab + (size_t)mrow * 128 + kc * 32 + koff);
        #pragma unroll
        for (int t = 0; t < 8; t++) {
            short8 b = *(const short8*)(Wp + (((t * 4 + kc) * 64 + lane) << 3));
            acc[t] = __builtin_amdgcn_mfma_f32_16x16x32_bf16(a, b, acc[t], 0, 0, 0);
        }
    }

    int rbase = wv * 16 + (lane >> 4) * 4;
    int col = lane & 15;
    #pragma unroll
    for (int t = 0; t < 8; t++)
        #pragma unroll
        for (int r = 0; r < 4; r++)
            tiles[(rbase + r) * 132 + t * 16 + col] = acc[t][r];
    __syncthreads();

    #pragma unroll
    for (int it = 0; it < 4; it++) {
        int u = tid + it * 256;
        int rl = u >> 4, cg = u & 15;
        int row = base + rl;
        if (row < M) {
            const float* p = tiles + rl * 132 + cg * 8;
            float4 v0 = *(const float4*)(p);
            float4 v1 = *(const float4*)(p + 4);
            uint4 o;
            o.x = f2bf(v0.x) | (f2bf(v0.y) << 16);
            o.y = f2bf(v0.z) | (f2bf(v0.w) << 16);
            o.z = f2bf(v1.x) | (f2bf(v1.y) << 16);
            o.w = f2bf(v1.z) | (f2bf(v1.w) << 16);
            *(uint4*)(Hb + (size_t)row * 128 + cg * 8) = o;
        }
    }

    {
        int rl = tid >> 2, hd = tid & 3;
        int row = base + rl;
        if (row < M) {
            const float* hrow = tiles + rl * 132 + hd * 32;
            const float* as = att_s + hd * 32;
            const float* ad = att_d + hd * 32;
            float ps = 0.f, pd = 0.f;
            #pragma unroll
            for (int i = 0; i < 8; i++) {
                float4 hv = *(const float4*)(hrow + i * 4);
                float4 sv = *(const float4*)(as + i * 4);
                float4 dv = *(const float4*)(ad + i * 4);
                ps += hv.x * sv.x + hv.y * sv.y + hv.z * sv.z + hv.w * sv.w;
                pd += hv.x * dv.x + hv.y * dv.y + hv.z * dv.z + hv.w * dv.w;
            }
            asn[row * 4 + hd] = ps;
            adn[row * 4 + hd] = pd;
        }
    }
}

// ------- aggregation + bias + BN + ELU (layers 0,1): one wave/node, channel-parallel -------
// No max-subtraction: logits are bounded (|e| ~ O(10)) so exp(e)/sum(exp(e)) is safe and
// mathematically identical to the stabilized form. Single edge sweep + phase C.

__global__ __launch_bounds__(256) void aggregate(
        const unsigned short* __restrict__ hb, const float* __restrict__ asn,
        const float* __restrict__ adn, const int* __restrict__ offs,
        const int* __restrict__ ssrc, const float* __restrict__ bias,
        const float* __restrict__ gamma, const float* __restrict__ beta,
        const float* __restrict__ rmean, const float* __restrict__ rvar,
        unsigned short* __restrict__ outb) {
    __shared__ int2 sPair[4][4][72];   // [wave][head][slot]; stride 72 -> heads offset 16 banks
    int wv = threadIdx.x >> 6;
    int node = blockIdx.x * 4 + wv;
    if (node >= N_NODES) return;
    int lane = threadIdx.x & 63;
    int hd = lane >> 4;
    int beg = offs[node], deg = offs[node + 1] - beg;
    float4 ad4 = *(const float4*)(adn + node * 4);

    if (lane < 32) sPair[wv][lane >> 3][64 + (lane & 7)] = make_int2(0, 0);

    float4 den4 = make_float4(0.f, 0.f, 0.f, 0.f);
    float acc0 = 0.f, acc1 = 0.f;
    const unsigned short* hlane = hb + 2 * lane;
    const int2* pp = &sPair[wv][hd][0];

    auto phaseC = [&](int cnt) {
        int bound = (cnt + 7) & ~7;
        for (int i = 0; i < bound; i += 8) {
            int2 p0 = pp[i],     p1 = pp[i + 1], p2 = pp[i + 2], p3 = pp[i + 3];
            int2 p4 = pp[i + 4], p5 = pp[i + 5], p6 = pp[i + 6], p7 = pp[i + 7];
            unsigned u0 = *(const unsigned*)(hlane + (((unsigned)p0.x) << 7));
            unsigned u1 = *(const unsigned*)(hlane + (((unsigned)p1.x) << 7));
            unsigned u2 = *(const unsigned*)(hlane + (((unsigned)p2.x) << 7));
            unsigned u3 = *(const unsigned*)(hlane + (((unsigned)p3.x) << 7));
            unsigned u4 = *(const unsigned*)(hlane + (((unsigned)p4.x) << 7));
            unsigned u5 = *(const unsigned*)(hlane + (((unsigned)p5.x) << 7));
            unsigned u6 = *(const unsigned*)(hlane + (((unsigned)p6.x) << 7));
            unsigned u7 = *(const unsigned*)(hlane + (((unsigned)p7.x) << 7));
            acc0 += __int_as_float(p0.y) * bflo(u0); acc1 += __int_as_float(p0.y) * bfhi(u0);
            acc0 += __int_as_float(p1.y) * bflo(u1); acc1 += __int_as_float(p1.y) * bfhi(u1);
            acc0 += __int_as_float(p2.y) * bflo(u2); acc1 += __int_as_float(p2.y) * bfhi(u2);
            acc0 += __int_as_float(p3.y) * bflo(u3); acc1 += __int_as_float(p3.y) * bfhi(u3);
            acc0 += __int_as_float(p4.y) * bflo(u4); acc1 += __int_as_float(p4.y) * bfhi(u4);
            acc0 += __int_as_float(p5.y) * bflo(u5); acc1 += __int_as_float(p5.y) * bfhi(u5);
            acc0 += __int_as_float(p6.y) * bflo(u6); acc1 += __int_as_float(p6.y) * bfhi(u6);
            acc0 += __int_as_float(p7.y) * bflo(u7); acc1 += __int_as_float(p7.y) * bfhi(u7);
        }
    };

    for (int base0 = 0; base0 < deg; base0 += 64) {
        int j = base0 + lane;
        int s = 0;
        float4 w4 = make_float4(0.f, 0.f, 0.f, 0.f);
        if (j < deg) {
            s = ssrc[beg + j];
            float4 a = *(const float4*)(asn + s * 4);
            w4.x = __expf(lrelu(a.x + ad4.x));
            w4.y = __expf(lrelu(a.y + ad4.y));
            w4.z = __expf(lrelu(a.z + ad4.z));
            w4.w = __expf(lrelu(a.w + ad4.w));
            den4.x += w4.x; den4.y += w4.y; den4.z += w4.z; den4.w += w4.w;
        }
        sPair[wv][0][lane] = make_int2(s, __float_as_int(w4.x));
        sPair[wv][1][lane] = make_int2(s, __float_as_int(w4.y));
        sPair[wv][2][lane] = make_int2(s, __float_as_int(w4.z));
        sPair[wv][3][lane] = make_int2(s, __float_as_int(w4.w));
        int cnt = deg - base0; if (cnt > 64) cnt = 64;
        phaseC(cnt);
    }

    #pragma unroll
    for (int off = 32; off; off >>= 1) {
        den4.x += __shfl_xor(den4.x, off);
        den4.y += __shfl_xor(den4.y, off);
        den4.z += __shfl_xor(den4.z, off);
        den4.w += __shfl_xor(den4.w, off);
    }
    float den = (hd & 2) ? ((hd & 1) ? den4.w : den4.z)
                         : ((hd & 1) ? den4.y : den4.x);
    float inv = 1.f / (den + 1e-16f);

    int c0 = lane * 2;
    float2 bi = *(const float2*)(bias + c0);
    float2 gm = *(const float2*)(gamma + c0);
    float2 bt = *(const float2*)(beta + c0);
    float2 rm = *(const float2*)(rmean + c0);
    float2 rv = *(const float2*)(rvar + c0);
    float o0 = acc0 * inv + bi.x;
    float o1 = acc1 * inv + bi.y;
    o0 = (o0 - rm.x) * rsqrtf(rv.x + EPS_BN) * gm.x + bt.x;
    o1 = (o1 - rm.y) * rsqrtf(rv.y + EPS_BN) * gm.y + bt.y;
    o0 = (o0 > 0.f) ? o0 : expm1f(o0);
    o1 = (o1 > 0.f) ? o1 : expm1f(o1);
    *(unsigned*)(outb + (size_t)node * 128 + c0) = f2bf(o0) | (f2bf(o1) << 16);
}

// ---------------- layer 2: fused GEMM(128->8) + attn coeffs (bf16 input) ----------------

__global__ __launch_bounds__(256) void gemm2_fused(
        const unsigned short* __restrict__ xb, const float* __restrict__ W2,
        const float* __restrict__ as2, const float* __restrict__ ad2,
        float* __restrict__ h2, float* __restrict__ asn, float* __restrict__ adn) {
    __shared__ float sW[128 * 8];
    __shared__ float sas[8], sad[8];
    int tid = threadIdx.x;
    for (int i = tid; i < 1024; i += 256) sW[i] = W2[i];
    if (tid < 8) { sas[tid] = as2[tid]; sad[tid] = ad2[tid]; }
    __syncthreads();
    int node = blockIdx.x * 256 + tid;
    if (node >= N_NODES) return;
    const uint4* xr = (const uint4*)(xb + (size_t)node * 128);
    float acc[8];
    #pragma unroll
    for (int c = 0; c < 8; c++) acc[c] = 0.f;
    for (int k8 = 0; k8 < 16; k8++) {
        uint4 u = xr[k8];
        float f[8] = { bflo(u.x), bfhi(u.x), bflo(u.y), bfhi(u.y),
                       bflo(u.z), bfhi(u.z), bflo(u.w), bfhi(u.w) };
        int kb = k8 * 8;
        #pragma unroll
        for (int q = 0; q < 8; q++)
            #pragma unroll
            for (int c = 0; c < 8; c++)
                acc[c] += f[q] * sW[(kb + q) * 8 + c];
    }
    float ps = 0.f, pd = 0.f;
    #pragma unroll
    for (int c = 0; c < 8; c++) {
        h2[(size_t)node * 8 + c] = acc[c];
        ps += acc[c] * sas[c];
        pd += acc[c] * sad[c];
    }
    asn[node] = ps;
    adn[node] = pd;
}

// ------- layer 2 aggregation + bias + log_softmax: one wave/node (no max pass) -------

__global__ __launch_bounds__(256) void aggregate2(
        const float* __restrict__ h2, const float* __restrict__ asn,
        const float* __restrict__ adn, const int* __restrict__ offs,
        const int* __restrict__ ssrc, const float* __restrict__ b2,
        float* __restrict__ out) {
    __shared__ int2 sPair[4][64];
    int wv = threadIdx.x >> 6;
    int node = blockIdx.x * 4 + wv;
    if (node >= N_NODES) return;
    int lane = threadIdx.x & 63;
    int g = lane >> 3, c = lane & 7;
    int beg = offs[node], end = offs[node + 1];
    int deg = end - beg;
    float adv = adn[node];

    float den = 0.f, acc = 0.f;
    auto phaseC = [&](int cnt) {
        int nIt = (cnt + 15) >> 4;
        const int2* pp = &sPair[wv][0];
        for (int i = 0; i < nIt; i++) {
            int e = i * 16 + g;
            int2 p0 = pp[e];
            int2 p1 = pp[e + 8];
            acc += __int_as_float(p0.y) * h2[(((unsigned)p0.x) << 3) + c];
            acc += __int_as_float(p1.y) * h2[(((unsigned)p1.x) << 3) + c];
        }
    };

    for (int base = 0; base < deg; base += 64) {
        int j = base + lane;
        int s = 0; float w = 0.f;
        if (j < deg) {
            s = ssrc[beg + j];
            w = __expf(lrelu(asn[s] + adv));
            den += w;
        }
        sPair[wv][lane] = make_int2(s, __float_as_int(w));
        int cnt = deg - base; if (cnt > 64) cnt = 64;
        phaseC(cnt);
    }

    acc += __shfl_xor(acc, 8); acc += __shfl_xor(acc, 16); acc += __shfl_xor(acc, 32);
    #pragma unroll
    for (int off = 32; off; off >>= 1) den += __shfl_xor(den, off);

    float o = acc / (den + 1e-16f) + b2[c];
    float mx = o;
    mx = fmaxf(mx, __shfl_xor(mx, 1));
    mx = fmaxf(mx, __shfl_xor(mx, 2));
    mx = fmaxf(mx, __shfl_xor(mx, 4));
    float ex = __expf(o - mx);
    float sm = ex;
    sm += __shfl_xor(sm, 1); sm += __shfl_xor(sm, 2); sm += __shfl_xor(sm, 4);
    if (g == 0) out[(size_t)node * 8 + c] = o - mx - logf(sm);
}

// ---------------- launch ----------------

extern "C" void kernel_launch(void* const* d_in, const int* in_sizes, int n_in,
                              void* d_out, int out_size, void* d_ws, size_t ws_size,
                              hipStream_t stream) {
    const float* x   = (const float*)d_in[0];
    const int*   ei  = (const int*)d_in[1];
    const float* W0  = (const float*)d_in[2];
    const float* as0 = (const float*)d_in[3];
    const float* ad0 = (const float*)d_in[4];
    const float* b0  = (const float*)d_in[5];
    const float* g0  = (const float*)d_in[6];
    const float* bb0 = (const float*)d_in[7];
    const float* rm0 = (const float*)d_in[8];
    const float* rv0 = (const float*)d_in[9];
    const float* W1  = (const float*)d_in[10];
    const float* as1 = (const float*)d_in[11];
    const float* ad1 = (const float*)d_in[12];
    const float* b1  = (const float*)d_in[13];
    const float* g1  = (const float*)d_in[14];
    const float* bb1 = (const float*)d_in[15];
    const float* rm1 = (const float*)d_in[16];
    const float* rv1 = (const float*)d_in[17];
    const float* W2  = (const float*)d_in[18];
    const float* as2 = (const float*)d_in[19];
    const float* ad2 = (const float*)d_in[20];
    const float* b2  = (const float*)d_in[21];
    float* out = (float*)d_out;

    char* w = (char*)d_ws;
    size_t off = 0;
    auto carve = [&](size_t bytes) {
        void* p = w + off;
        off += (bytes + 255) & ~(size_t)255;
        return p;
    };
    unsigned short* xb   = (unsigned short*)carve((size_t)N_NODES * 128 * 2);
    unsigned short* Hb   = (unsigned short*)carve((size_t)N_NODES * 128 * 2);
    unsigned short* Xb   = (unsigned short*)carve((size_t)N_NODES * 128 * 2);
    unsigned short* W0p  = (unsigned short*)carve(16384 * 2);
    unsigned short* W1p  = (unsigned short*)carve(16384 * 2);
    int*   offs   = (int*)carve((size_t)(N_NODES + 1) * 4);
    int*   bhist  = (int*)carve((size_t)NBUCK * 4);
    int*   boffs  = (int*)carve((size_t)(NBUCK + 1) * 4);
    int*   bcur   = (int*)carve((size_t)NBUCK * 4);
    int*   ssrc   = (int*)carve((size_t)ET * 4);
    int2*  pairs  = (int2*)carve((size_t)ET * 8);
    float* asn    = (float*)carve((size_t)N_NODES * 4 * 4);
    float* adn    = (float*)carve((size_t)N_NODES * 4 * 4);
    float* h2     = (float*)carve((size_t)N_NODES * 8 * 4);
    float* as2n   = (float*)carve((size_t)N_NODES * 4);
    float* ad2n   = (float*)carve((size_t)N_NODES * 4);
    (void)ws_size; (void)in_sizes; (void)n_in; (void)out_size;

    const int NB = (N_NODES + 255) / 256;
    const int GB = (N_NODES + 63) / 64;
    const int PB = (ET + EPB - 1) / EPB;

    hipMemsetAsync(bhist, 0, (size_t)NBUCK * 4, stream);
    bucket_hist<<<PB, 256, 0, stream>>>(ei, bhist);
    scan_buckets<<<1, 256, 0, stream>>>(bhist, boffs, bcur, offs);
    partition_pairs<<<PB, 256, 0, stream>>>(ei, bcur, pairs);
    group_bucket<<<NBUCK, 256, 0, stream>>>(pairs, boffs, offs, ssrc);

    prep_inputs<<<CAST_B + 2 * PACK_B, 256, 0, stream>>>(x, xb, W0, W0p, W1, W1p);

    gemm_attn<<<GB, 256, 0, stream>>>(xb, W0p, as0, ad0, Hb, asn, adn, N_NODES);
    aggregate<<<(N_NODES + 3) / 4, 256, 0, stream>>>(Hb, asn, adn, offs, ssrc,
                                                     b0, g0, bb0, rm0, rv0, Xb);
    gemm_attn<<<GB, 256, 0, stream>>>(Xb, W1p, as1, ad1, Hb, asn, adn, N_NODES);
    aggregate<<<(N_NODES + 3) / 4, 256, 0, stream>>>(Hb, asn, adn, offs, ssrc,
                                                     b1, g1, bb1, rm1, rv1, Xb);
    gemm2_fused<<<NB, 256, 0, stream>>>(Xb, W2, as2, ad2, h2, as2n, ad2n);
    aggregate2<<<(N_NODES + 3) / 4, 256, 0, stream>>>(h2, as2n, ad2n, offs, ssrc, b2, out);
}